// Round 2
// baseline (432.443 us; speedup 1.0000x reference)
//
#include <hip/hip_runtime.h>

// MQA: B=2, S=2048, D=2048, H=16, HD=128.  GEMMs bf16 MFMA 16x16x32, fp32 acc.
// v6: attention restructured to 8 waves x 16 q-rows (512 thr, 4 waves/SIMD)
// and PV merged to mfma 16x16x32 via in-register k-permutation (no shuffles).
// setprio(1) around MFMA clusters. GEMM core unchanged (double-buffered,
// 1 barrier/iter). Q-proj + KV-proj fused; 4 transposes fused.
// (Resubmit: round-1 bench was an infra failure; kernel never ran.)

typedef unsigned short u16;
typedef __attribute__((ext_vector_type(8))) short bf16x8;   // 8 bf16 = 4 VGPR
typedef __attribute__((ext_vector_type(4))) short bf16x4;   // 4 bf16 = 2 VGPR
typedef __attribute__((ext_vector_type(4))) float f32x4;

#define D_MODEL 2048
#define SEQ     2048
#define NH      16
#define HD      128
#define BK      32

__device__ __forceinline__ u16 f2bf(float f){
  union { float f; unsigned u; } v; v.f = f;
  unsigned r = (v.u + 0x7FFFu + ((v.u >> 16) & 1u)) >> 16;  // RNE
  return (u16)r;
}

#if __has_builtin(__builtin_amdgcn_cvt_pk_bf16_f32)
__device__ __forceinline__ unsigned pack2bf(float a, float b){
  auto v = __builtin_amdgcn_cvt_pk_bf16_f32(a, b);
  unsigned u; __builtin_memcpy(&u, &v, 4); return u;
}
#else
__device__ __forceinline__ unsigned pack2bf(float a, float b){
  return (unsigned)f2bf(a) | ((unsigned)f2bf(b) << 16);
}
#endif

__device__ __forceinline__ void gll16(const void* g, void* l){
  __builtin_amdgcn_global_load_lds(
      (const __attribute__((address_space(1))) void*)g,
      (__attribute__((address_space(3))) void*)l, 16, 0, 0);
}

// ---------------- fp32 -> bf16 conversion of q,k,v ----------------
__global__ __launch_bounds__(256) void convert3_kernel(
    const float4* __restrict__ a, const float4* __restrict__ b, const float4* __restrict__ c,
    ushort4* __restrict__ oa, ushort4* __restrict__ ob, ushort4* __restrict__ oc){
  int i = blockIdx.x*256 + threadIdx.x;
  float4 va = a[i], vb = b[i], vc = c[i];
  ushort4 ra, rb, rc;
  ra.x=f2bf(va.x); ra.y=f2bf(va.y); ra.z=f2bf(va.z); ra.w=f2bf(va.w);
  rb.x=f2bf(vb.x); rb.y=f2bf(vb.y); rb.z=f2bf(vb.z); rb.w=f2bf(vb.w);
  rc.x=f2bf(vc.x); rc.y=f2bf(vc.y); rc.z=f2bf(vc.z); rc.w=f2bf(vc.w);
  oa[i]=ra; ob[i]=rb; oc[i]=rc;
}

// ---------------- all 4 weight transposes in one launch ----------------
__global__ __launch_bounds__(256) void transpose_all(
    const float* __restrict__ Wq, const float* __restrict__ Wo,
    const float* __restrict__ Wk, const float* __restrict__ Wv,
    u16* __restrict__ WqT, u16* __restrict__ WoT,
    u16* __restrict__ WkT, u16* __restrict__ WvT){
  __shared__ float tt[32][33];
  int id = blockIdx.x;
  const float* in; u16* outp; int C, bx, by;
  if (id < 4096)      { in=Wq; outp=WqT; C=2048; bx=id&63;        by=id>>6; }
  else if (id < 8192) { id-=4096; in=Wo; outp=WoT; C=2048; bx=id&63; by=id>>6; }
  else if (id < 8448) { id-=8192; in=Wk; outp=WkT; C=128;  bx=id&3;  by=id>>2; }
  else                { id-=8448; in=Wv; outp=WvT; C=128;  bx=id&3;  by=id>>2; }
  const int R = 2048;
  int c0 = bx*32, r0 = by*32;
  int tx = threadIdx.x & 31, ty = threadIdx.x >> 5;   // (32,8) flattened
  #pragma unroll
  for (int k=0;k<4;k++) tt[ty+k*8][tx] = in[(size_t)(r0+ty+k*8)*C + c0+tx];
  __syncthreads();
  #pragma unroll
  for (int k=0;k<4;k++) outp[(size_t)(c0+ty+k*8)*R + r0+tx] = f2bf(tt[tx][ty+k*8]);
}

// ---------------- double-buffered GEMM core: 1 barrier/iter ----------------
__device__ __forceinline__ void gemm_core_db(
    const u16* __restrict__ A, const u16* __restrict__ BT,
    int lda, int ldb, int m0, int n0, int kbeg, int kend,
    u16* As, u16* Bs, f32x4 acc[4][4])
{
  const int t = threadIdx.x;
  const int w = t >> 6, l = t & 63;
  const int wr = w >> 1, wc = w & 1;
  const int c16 = l & 15, q = l >> 4;
  const int srow = l >> 2;
  const int sc   = ((l & 3) ^ ((l >> 3) & 3)) * 8;

  int aoff[4], boff[4];
  #pragma unroll
  for (int mt=0;mt<4;mt++){
    int row = wr*64 + mt*16 + c16;
    aoff[mt] = row*BK + ((q ^ ((row>>1)&3))*8);
  }
  #pragma unroll
  for (int nt=0;nt<4;nt++){
    int row = wc*64 + nt*16 + c16;
    boff[nt] = row*BK + ((q ^ ((row>>1)&3))*8);
  }

  auto issue = [&](int k0, int buf){
    u16* Ad = As + buf*4096;
    u16* Bd = Bs + buf*4096;
    #pragma unroll
    for (int half=0; half<2; half++){
      int r = half*64 + w*16 + srow;
      gll16(A  + (size_t)(m0+r)*lda + k0 + sc, Ad + (half*64 + w*16)*BK);
      gll16(BT + (size_t)(n0+r)*ldb + k0 + sc, Bd + (half*64 + w*16)*BK);
    }
  };

  const int n = (kend - kbeg) / BK;
  issue(kbeg, 0);
  for (int i = 0; i < n; i++){
    __syncthreads();                       // tile i arrived; buf (i+1)&1 free
    if (i+1 < n) issue(kbeg + (i+1)*BK, (i+1)&1);
    const u16* Ab = As + (i&1)*4096;
    const u16* Bb = Bs + (i&1)*4096;
    bf16x8 af[4], bfr[4];
    #pragma unroll
    for (int mt=0;mt<4;mt++) af[mt]  = *(const bf16x8*)(Ab + aoff[mt]);
    #pragma unroll
    for (int nt=0;nt<4;nt++) bfr[nt] = *(const bf16x8*)(Bb + boff[nt]);
    #pragma unroll
    for (int mt=0;mt<4;mt++)
      #pragma unroll
      for (int nt=0;nt<4;nt++)
        acc[mt][nt] = __builtin_amdgcn_mfma_f32_16x16x32_bf16(af[mt], bfr[nt], acc[mt][nt], 0,0,0);
  }
}

// ---------------- fused Q-projection + K/V projection ----------------
__global__ __launch_bounds__(256) void proj_kernel(
    const u16* __restrict__ qb, const u16* __restrict__ kb, const u16* __restrict__ vb,
    const u16* __restrict__ WqT, const u16* __restrict__ WkT, const u16* __restrict__ WvT,
    const float* __restrict__ bq, u16* __restrict__ Qp, float* __restrict__ part)
{
  __shared__ u16 As[2*4096], Bs[2*4096];
  f32x4 acc[4][4];
  f32x4 z = {0.f,0.f,0.f,0.f};
  #pragma unroll
  for (int i=0;i<4;i++) for (int j=0;j<4;j++) acc[i][j] = z;
  const int t = threadIdx.x, w = t>>6, l = t&63, wr = w>>1, wc = w&1, c16 = l&15, q = l>>4;
  int id = blockIdx.x;
  if (id < 512){
    int m0 = (id & 31)*128, n0 = (id >> 5)*128;
    gemm_core_db(qb, WqT, 2048, 2048, m0, n0, 0, 2048, As, Bs, acc);
    #pragma unroll
    for (int mt=0;mt<4;mt++)
      #pragma unroll
      for (int nt=0;nt<4;nt++){
        int col = n0 + wc*64 + nt*16 + c16;
        float bv = bq[col];
        #pragma unroll
        for (int r=0;r<4;r++){
          int row = m0 + wr*64 + mt*16 + q*4 + r;
          Qp[(size_t)row*D_MODEL + col] = f2bf(acc[mt][nt][r] + bv);
        }
      }
  } else {
    int kvid = id - 512;
    int zi = kvid & 3, nb = (kvid >> 2) & 1, mi = kvid >> 3;
    const u16* Am = nb ? vb  : kb;
    const u16* Bm = nb ? WvT : WkT;
    gemm_core_db(Am, Bm, 2048, 2048, mi*128, 0, zi*512, zi*512+512, As, Bs, acc);
    float* dst = part + (size_t)(zi*2 + nb)*524288;   // [z][nb][4096][128]
    #pragma unroll
    for (int mt=0;mt<4;mt++)
      #pragma unroll
      for (int nt=0;nt<4;nt++){
        int col = wc*64 + nt*16 + c16;
        #pragma unroll
        for (int r=0;r<4;r++){
          int row = mi*128 + wr*64 + mt*16 + q*4 + r;
          dst[(size_t)row*128 + col] = acc[mt][nt][r];
        }
      }
  }
}

// ---------------- O-projection GEMM + bias, fp32 out ----------------
__global__ __launch_bounds__(256) void oproj_kernel(
    const u16* __restrict__ A, const u16* __restrict__ BT, const float* __restrict__ bias,
    float* __restrict__ C)
{
  __shared__ u16 As[2*4096], Bs[2*4096];
  f32x4 acc[4][4];
  f32x4 z = {0.f,0.f,0.f,0.f};
  #pragma unroll
  for (int i=0;i<4;i++) for (int j=0;j<4;j++) acc[i][j] = z;
  int m0 = blockIdx.x*128, n0 = blockIdx.y*128;
  gemm_core_db(A, BT, 2048, 2048, m0, n0, 0, 2048, As, Bs, acc);
  const int t = threadIdx.x, w = t>>6, l = t&63, wr = w>>1, wc = w&1, c16 = l&15, q = l>>4;
  #pragma unroll
  for (int mt=0;mt<4;mt++)
    #pragma unroll
    for (int nt=0;nt<4;nt++){
      int col = n0 + wc*64 + nt*16 + c16;
      float bv = bias[col];
      #pragma unroll
      for (int r=0;r<4;r++){
        int row = m0 + wr*64 + mt*16 + q*4 + r;
        C[(size_t)row*D_MODEL + col] = acc[mt][nt][r] + bv;
      }
    }
}

// ---------------- reduce split-K partials; Kp bf16 [4096][128], VpT bf16 [B][128][S] ----------------
__global__ __launch_bounds__(256) void kv_reduce_kernel(
    const float* __restrict__ part, const float* __restrict__ bk, const float* __restrict__ bv,
    u16* __restrict__ Kp, u16* __restrict__ VpT){
  int idx = blockIdx.x*256 + threadIdx.x;
  int d = idx & 127, sg = idx >> 7;
  float ka = 0.f, va = 0.f;
  #pragma unroll
  for (int zi=0; zi<4; zi++){
    ka += part[(size_t)(zi*2+0)*524288 + idx];
    va += part[(size_t)(zi*2+1)*524288 + idx];
  }
  Kp[idx] = f2bf(ka + bk[d]);
  int b = sg >> 11, sl = sg & 2047;
  VpT[(size_t)b*262144 + (size_t)d*2048 + sl] = f2bf(va + bv[d]);
}

// ---------------- flash attention v6 ----------------
// 8 waves x 16 q-rows (512 thr) -> 4 waves/SIMD. K-tile 128 keys, 16 iters.
// V_kt gll at iter top (drained by mid-barrier); K_{kt+1} gll after mid-barrier
// (drained by end-barrier). PV uses mfma 16x16x32: within each 32-k block the
// k-axis is fed in the permuted order the lanes already hold (lane q supplies
// k = {4q..4q+3} then {16+4q..16+4q+3}); V^T fragments are read in the SAME
// permuted order, so the contraction is exact with zero cross-lane traffic.
// LDS 64 KB: Ks[128key][128d] | Vs[128d][128k], chunk8-XOR swizzled.
__global__ __launch_bounds__(512, 4) void attn_kernel(
    const u16* __restrict__ Qp, const u16* __restrict__ Kp,
    const u16* __restrict__ VpT, u16* __restrict__ attnb){
  __shared__ u16 lds[32768];
  u16* Ks = lds;            // 128 x 128
  u16* Vs = lds + 16384;    // 128 x 128 (V^T)
  const int t = threadIdx.x;
  const int w = t >> 6, l = t & 63;
  const int c16 = l & 15, q = l >> 4;

  const int qt = blockIdx.x;           // 0..15
  const int bh = blockIdx.y;           // 0..31
  const int b = bh >> 4, h = bh & 15;

  const u16* Qbase = Qp  + ((size_t)(b*SEQ + qt*128 + w*16))*D_MODEL + h*HD;
  const u16* Kbase = Kp  + (size_t)(b*SEQ)*HD;
  const u16* Vbase = VpT + (size_t)b*HD*SEQ;

  // ---- prologue: stage Q (per-wave 16 rows) into Vs region + K tile 0 ----
  {
    u16* qtmp = Vs + w*2048;           // 16 rows x 128
    #pragma unroll
    for (int j=0;j<4;j++){
      int r = j*4 + (l >> 4);
      int g = (l & 15) ^ (r & 15);
      gll16(Qbase + (size_t)r*D_MODEL + g*8, qtmp + j*512);
    }
  }
  #pragma unroll
  for (int j=0;j<4;j++){
    int r = j*32 + w*4 + (l >> 4);
    int g = (l & 15) ^ (r & 15);
    gll16(Kbase + (size_t)r*HD + g*8, Ks + j*4096 + w*512);
  }
  __syncthreads();   // Q + K0 arrived
  bf16x8 qf[4];
  #pragma unroll
  for (int kk=0;kk<4;kk++){
    int ch = kk*4 + q;
    qf[kk] = *(const bf16x8*)(Vs + w*2048 + c16*128 + ((ch ^ c16) & 15)*8);
  }
  __syncthreads();   // all waves done reading Q scratch (Vs region now free)

  f32x4 o[8];
  f32x4 z4 = {0.f,0.f,0.f,0.f};
  #pragma unroll
  for (int dt=0;dt<8;dt++) o[dt] = z4;
  float mrow = -1e30f, lrow = 0.f;
  const float cs = 0.08838834764831845f * 1.4426950408889634f;  // (1/sqrt(128))*log2(e)

  for (int kt = 0; kt < 16; kt++){
    // issue V_kt gll now — overlaps QK + softmax; drained by mid-barrier
    #pragma unroll
    for (int j=0;j<4;j++){
      int d = j*32 + w*4 + (l >> 4);
      int g = (l & 15) ^ (d & 15);
      gll16(Vbase + (size_t)d*SEQ + kt*128 + g*8, Vs + j*4096 + w*512);
    }

    // S^T = K Q^T : lane q-col=c16, key rows quad*4+r (+16*kt8)
    f32x4 s[8];
    #pragma unroll
    for (int kt8=0;kt8<8;kt8++) s[kt8] = z4;
    __builtin_amdgcn_s_setprio(1);
    #pragma unroll
    for (int kt8=0; kt8<8; kt8++){
      #pragma unroll
      for (int kk=0;kk<4;kk++){
        int ch = kk*4 + q;
        bf16x8 kf = *(const bf16x8*)(Ks + (kt8*16 + c16)*128 + ((ch ^ c16) & 15)*8);
        s[kt8] = __builtin_amdgcn_mfma_f32_16x16x32_bf16(kf, qf[kk], s[kt8], 0,0,0);
      }
    }
    __builtin_amdgcn_s_setprio(0);

    // online softmax: 32 in-lane values + 2 cross-quad shuffles (tree form)
    float x[8];
    #pragma unroll
    for (int kt8=0;kt8<8;kt8++)
      x[kt8] = fmaxf(fmaxf(s[kt8][0],s[kt8][1]), fmaxf(s[kt8][2],s[kt8][3]));
    float vmax = fmaxf(fmaxf(fmaxf(x[0],x[1]),fmaxf(x[2],x[3])),
                       fmaxf(fmaxf(x[4],x[5]),fmaxf(x[6],x[7])));
    vmax = fmaxf(vmax, __shfl_xor(vmax, 16));
    vmax = fmaxf(vmax, __shfl_xor(vmax, 32));
    float mnew = fmaxf(mrow, vmax);
    float alpha = exp2f((mrow - mnew)*cs);
    float mc = mnew*cs;
    float rs[8];
    #pragma unroll
    for (int kt8=0;kt8<8;kt8++){
      float p0 = exp2f(__builtin_fmaf(s[kt8][0], cs, -mc));
      float p1 = exp2f(__builtin_fmaf(s[kt8][1], cs, -mc));
      float p2 = exp2f(__builtin_fmaf(s[kt8][2], cs, -mc));
      float p3 = exp2f(__builtin_fmaf(s[kt8][3], cs, -mc));
      s[kt8][0]=p0; s[kt8][1]=p1; s[kt8][2]=p2; s[kt8][3]=p3;
      rs[kt8] = (p0+p1)+(p2+p3);
    }
    float rsum = ((rs[0]+rs[1])+(rs[2]+rs[3])) + ((rs[4]+rs[5])+(rs[6]+rs[7]));
    rsum += __shfl_xor(rsum, 16);
    rsum += __shfl_xor(rsum, 32);
    lrow = lrow*alpha + rsum;
    mrow = mnew;

    // rescale O (skip when no lane's max moved — exact)
    unsigned long long allone = __ballot(alpha == 1.f);
    if (allone != ~0ull){
      #pragma unroll
      for (int dt=0;dt<8;dt++)
        #pragma unroll
        for (int r=0;r<4;r++) o[dt][r] *= alpha;
    }

    // pack P to bf16: P32[kb] = B-operand for the kb-th 32-k block
    // (slots 0..3 = k 32kb+4q+r, slots 4..7 = k 32kb+16+4q+r)
    union PU { unsigned u[4]; bf16x8 v; } P32[4];
    #pragma unroll
    for (int kb=0;kb<4;kb++){
      P32[kb].u[0] = pack2bf(s[2*kb][0],   s[2*kb][1]);
      P32[kb].u[1] = pack2bf(s[2*kb][2],   s[2*kb][3]);
      P32[kb].u[2] = pack2bf(s[2*kb+1][0], s[2*kb+1][1]);
      P32[kb].u[3] = pack2bf(s[2*kb+1][2], s[2*kb+1][3]);
    }

    __syncthreads();   // mid: V_kt arrived; all QK reads of Ks done

    // issue K_{kt+1} gll now — overlaps PV; drained by end-barrier
    if (kt < 15){
      #pragma unroll
      for (int j=0;j<4;j++){
        int r = j*32 + w*4 + (l >> 4);
        int g = (l & 15) ^ (r & 15);
        gll16(Kbase + (size_t)((kt+1)*128 + r)*HD + g*8, Ks + j*4096 + w*512);
      }
    }

    // O^T += V^T P^T : A = V^T frags in the lane-held permuted k order
    __builtin_amdgcn_s_setprio(1);
    #pragma unroll
    for (int kb=0; kb<4; kb++){
      int ca = 4*kb + (q>>1);       // chunk for k=32kb+4q (half q&1)
      int cb = ca + 2;              // chunk for k=32kb+16+4q
      #pragma unroll
      for (int dt=0; dt<8; dt++){
        int d = dt*16 + c16;
        union VU { bf16x4 h[2]; bf16x8 v; } vf;
        vf.h[0] = *(const bf16x4*)(Vs + d*128 + ((ca ^ c16) & 15)*8 + (q&1)*4);
        vf.h[1] = *(const bf16x4*)(Vs + d*128 + ((cb ^ c16) & 15)*8 + (q&1)*4);
        o[dt] = __builtin_amdgcn_mfma_f32_16x16x32_bf16(vf.v, P32[kb].v, o[dt], 0,0,0);
      }
    }
    __builtin_amdgcn_s_setprio(0);
    __syncthreads();   // end: K_{kt+1} arrived; all PV reads of Vs done
  }

  // normalize + write: lane holds O[q=c16][d=dt*16+quad*4+r] -> ushort4 along d
  float inv = 1.f / lrow;
  int qrow = qt*128 + w*16 + c16;
  u16* dst = attnb + ((size_t)(b*SEQ) + qrow)*D_MODEL + h*HD + q*4;
  #pragma unroll
  for (int dt=0;dt<8;dt++){
    ushort4 pk;
    pk.x = f2bf(o[dt][0]*inv);
    pk.y = f2bf(o[dt][1]*inv);
    pk.z = f2bf(o[dt][2]*inv);
    pk.w = f2bf(o[dt][3]*inv);
    *(ushort4*)(dst + dt*16) = pk;
  }
}

extern "C" void kernel_launch(void* const* d_in, const int* in_sizes, int n_in,
                              void* d_out, int out_size, void* d_ws, size_t ws_size,
                              hipStream_t stream) {
  (void)in_sizes; (void)n_in; (void)out_size; (void)ws_size;
  const float* query = (const float*)d_in[0];
  const float* key   = (const float*)d_in[1];
  const float* value = (const float*)d_in[2];
  const float* Wq    = (const float*)d_in[3];
  const float* bq    = (const float*)d_in[4];
  const float* Wk    = (const float*)d_in[5];
  const float* bk    = (const float*)d_in[6];
  const float* Wv    = (const float*)d_in[7];
  const float* bv    = (const float*)d_in[8];
  const float* Wo    = (const float*)d_in[9];
  const float* bo    = (const float*)d_in[10];
  float* out = (float*)d_out;

  char* W = (char*)d_ws;
  u16*  qb     = (u16*) (W + 0);          // 16 MB  bf16 query [4096][2048]
  u16*  kb     = (u16*) (W + 16777216);   // 16 MB  bf16 key
  u16*  vb     = (u16*) (W + 33554432);   // 16 MB  bf16 value
  u16*  WqT    = (u16*) (W + 50331648);   //  8 MB  Wq^T  [2048][2048]
  u16*  WoT    = (u16*) (W + 58720256);   //  8 MB  Wo^T
  u16*  WkT    = (u16*) (W + 67108864);   // .5 MB  Wk^T  [128][2048]
  u16*  WvT    = (u16*) (W + 67633152);   // .5 MB  Wv^T
  u16*  Qp     = (u16*) (W + 68157440);   // 16 MB  Q proj bf16 [4096][2048]
  u16*  Kp     = (u16*) (W + 84934656);   //  1 MB  K proj bf16 [4096][128]
  u16*  VpT    = (u16*) (W + 85983232);   //  1 MB  V proj^T bf16 [B][128][2048]
  u16*  attnb  = (u16*) (W + 87031808);   // 16 MB  attention out bf16 [4096][2048]
  float* kvpart= (float*)(W + 103809024); // 16 MB  split-K partials [4][2][4096][128]

  convert3_kernel<<<8192, 256, 0, stream>>>(
      (const float4*)query, (const float4*)key, (const float4*)value,
      (ushort4*)qb, (ushort4*)kb, (ushort4*)vb);
  transpose_all<<<8704, 256, 0, stream>>>(Wq, Wo, Wk, Wv, WqT, WoT, WkT, WvT);
  proj_kernel<<<768, 256, 0, stream>>>(qb, kb, vb, WqT, WkT, WvT, bq, Qp, kvpart);
  kv_reduce_kernel<<<2048, 256, 0, stream>>>(kvpart, bk, bv, Kp, VpT);
  attn_kernel<<<dim3(16,32), 512, 0, stream>>>(Qp, Kp, VpT, attnb);
  oproj_kernel<<<dim3(32,16), 256, 0, stream>>>(attnb, WoT, bo, out);
}

// Round 3
// 410.615 us; speedup vs baseline: 1.0532x; 1.0532x over previous
//
#include <hip/hip_runtime.h>

// MQA: B=2, S=2048, D=2048, H=16, HD=128.  GEMMs bf16 MFMA 16x16x32, fp32 acc.
// v7: attention = 8 waves x 32 q-rows (2 q-sets) per 512-thr block; 256 q-rows
// per block, grid (8,32) = 256 blocks = 1/CU. Every K/V LDS fragment feeds 2
// MFMAs (FLOP/LDS-byte = 32). PV merged K=32 (v6 permutation, verified). Q
// fragments loaded global->reg directly (no LDS staging). launch_bounds(512,2)
// -> 256-VGPR cap, no spills (v6's 128-cap spilled: WRITE_SIZE 19->46 MB).
// GEMM core unchanged; Q-proj + KV-proj fused; 4 transposes fused.

typedef unsigned short u16;
typedef __attribute__((ext_vector_type(8))) short bf16x8;   // 8 bf16 = 4 VGPR
typedef __attribute__((ext_vector_type(4))) short bf16x4;   // 4 bf16 = 2 VGPR
typedef __attribute__((ext_vector_type(4))) float f32x4;

#define D_MODEL 2048
#define SEQ     2048
#define NH      16
#define HD      128
#define BK      32

__device__ __forceinline__ u16 f2bf(float f){
  union { float f; unsigned u; } v; v.f = f;
  unsigned r = (v.u + 0x7FFFu + ((v.u >> 16) & 1u)) >> 16;  // RNE
  return (u16)r;
}

#if __has_builtin(__builtin_amdgcn_cvt_pk_bf16_f32)
__device__ __forceinline__ unsigned pack2bf(float a, float b){
  auto v = __builtin_amdgcn_cvt_pk_bf16_f32(a, b);
  unsigned u; __builtin_memcpy(&u, &v, 4); return u;
}
#else
__device__ __forceinline__ unsigned pack2bf(float a, float b){
  return (unsigned)f2bf(a) | ((unsigned)f2bf(b) << 16);
}
#endif

__device__ __forceinline__ void gll16(const void* g, void* l){
  __builtin_amdgcn_global_load_lds(
      (const __attribute__((address_space(1))) void*)g,
      (__attribute__((address_space(3))) void*)l, 16, 0, 0);
}

// ---------------- fp32 -> bf16 conversion of q,k,v ----------------
__global__ __launch_bounds__(256) void convert3_kernel(
    const float4* __restrict__ a, const float4* __restrict__ b, const float4* __restrict__ c,
    ushort4* __restrict__ oa, ushort4* __restrict__ ob, ushort4* __restrict__ oc){
  int i = blockIdx.x*256 + threadIdx.x;
  float4 va = a[i], vb = b[i], vc = c[i];
  ushort4 ra, rb, rc;
  ra.x=f2bf(va.x); ra.y=f2bf(va.y); ra.z=f2bf(va.z); ra.w=f2bf(va.w);
  rb.x=f2bf(vb.x); rb.y=f2bf(vb.y); rb.z=f2bf(vb.z); rb.w=f2bf(vb.w);
  rc.x=f2bf(vc.x); rc.y=f2bf(vc.y); rc.z=f2bf(vc.z); rc.w=f2bf(vc.w);
  oa[i]=ra; ob[i]=rb; oc[i]=rc;
}

// ---------------- all 4 weight transposes in one launch ----------------
__global__ __launch_bounds__(256) void transpose_all(
    const float* __restrict__ Wq, const float* __restrict__ Wo,
    const float* __restrict__ Wk, const float* __restrict__ Wv,
    u16* __restrict__ WqT, u16* __restrict__ WoT,
    u16* __restrict__ WkT, u16* __restrict__ WvT){
  __shared__ float tt[32][33];
  int id = blockIdx.x;
  const float* in; u16* outp; int C, bx, by;
  if (id < 4096)      { in=Wq; outp=WqT; C=2048; bx=id&63;        by=id>>6; }
  else if (id < 8192) { id-=4096; in=Wo; outp=WoT; C=2048; bx=id&63; by=id>>6; }
  else if (id < 8448) { id-=8192; in=Wk; outp=WkT; C=128;  bx=id&3;  by=id>>2; }
  else                { id-=8448; in=Wv; outp=WvT; C=128;  bx=id&3;  by=id>>2; }
  const int R = 2048;
  int c0 = bx*32, r0 = by*32;
  int tx = threadIdx.x & 31, ty = threadIdx.x >> 5;   // (32,8) flattened
  #pragma unroll
  for (int k=0;k<4;k++) tt[ty+k*8][tx] = in[(size_t)(r0+ty+k*8)*C + c0+tx];
  __syncthreads();
  #pragma unroll
  for (int k=0;k<4;k++) outp[(size_t)(c0+ty+k*8)*R + r0+tx] = f2bf(tt[tx][ty+k*8]);
}

// ---------------- double-buffered GEMM core: 1 barrier/iter ----------------
__device__ __forceinline__ void gemm_core_db(
    const u16* __restrict__ A, const u16* __restrict__ BT,
    int lda, int ldb, int m0, int n0, int kbeg, int kend,
    u16* As, u16* Bs, f32x4 acc[4][4])
{
  const int t = threadIdx.x;
  const int w = t >> 6, l = t & 63;
  const int wr = w >> 1, wc = w & 1;
  const int c16 = l & 15, q = l >> 4;
  const int srow = l >> 2;
  const int sc   = ((l & 3) ^ ((l >> 3) & 3)) * 8;

  int aoff[4], boff[4];
  #pragma unroll
  for (int mt=0;mt<4;mt++){
    int row = wr*64 + mt*16 + c16;
    aoff[mt] = row*BK + ((q ^ ((row>>1)&3))*8);
  }
  #pragma unroll
  for (int nt=0;nt<4;nt++){
    int row = wc*64 + nt*16 + c16;
    boff[nt] = row*BK + ((q ^ ((row>>1)&3))*8);
  }

  auto issue = [&](int k0, int buf){
    u16* Ad = As + buf*4096;
    u16* Bd = Bs + buf*4096;
    #pragma unroll
    for (int half=0; half<2; half++){
      int r = half*64 + w*16 + srow;
      gll16(A  + (size_t)(m0+r)*lda + k0 + sc, Ad + (half*64 + w*16)*BK);
      gll16(BT + (size_t)(n0+r)*ldb + k0 + sc, Bd + (half*64 + w*16)*BK);
    }
  };

  const int n = (kend - kbeg) / BK;
  issue(kbeg, 0);
  for (int i = 0; i < n; i++){
    __syncthreads();                       // tile i arrived; buf (i+1)&1 free
    if (i+1 < n) issue(kbeg + (i+1)*BK, (i+1)&1);
    const u16* Ab = As + (i&1)*4096;
    const u16* Bb = Bs + (i&1)*4096;
    bf16x8 af[4], bfr[4];
    #pragma unroll
    for (int mt=0;mt<4;mt++) af[mt]  = *(const bf16x8*)(Ab + aoff[mt]);
    #pragma unroll
    for (int nt=0;nt<4;nt++) bfr[nt] = *(const bf16x8*)(Bb + boff[nt]);
    #pragma unroll
    for (int mt=0;mt<4;mt++)
      #pragma unroll
      for (int nt=0;nt<4;nt++)
        acc[mt][nt] = __builtin_amdgcn_mfma_f32_16x16x32_bf16(af[mt], bfr[nt], acc[mt][nt], 0,0,0);
  }
}

// ---------------- fused Q-projection + K/V projection ----------------
__global__ __launch_bounds__(256) void proj_kernel(
    const u16* __restrict__ qb, const u16* __restrict__ kb, const u16* __restrict__ vb,
    const u16* __restrict__ WqT, const u16* __restrict__ WkT, const u16* __restrict__ WvT,
    const float* __restrict__ bq, u16* __restrict__ Qp, float* __restrict__ part)
{
  __shared__ u16 As[2*4096], Bs[2*4096];
  f32x4 acc[4][4];
  f32x4 z = {0.f,0.f,0.f,0.f};
  #pragma unroll
  for (int i=0;i<4;i++) for (int j=0;j<4;j++) acc[i][j] = z;
  const int t = threadIdx.x, w = t>>6, l = t&63, wr = w>>1, wc = w&1, c16 = l&15, q = l>>4;
  int id = blockIdx.x;
  if (id < 512){
    int m0 = (id & 31)*128, n0 = (id >> 5)*128;
    gemm_core_db(qb, WqT, 2048, 2048, m0, n0, 0, 2048, As, Bs, acc);
    #pragma unroll
    for (int mt=0;mt<4;mt++)
      #pragma unroll
      for (int nt=0;nt<4;nt++){
        int col = n0 + wc*64 + nt*16 + c16;
        float bv = bq[col];
        #pragma unroll
        for (int r=0;r<4;r++){
          int row = m0 + wr*64 + mt*16 + q*4 + r;
          Qp[(size_t)row*D_MODEL + col] = f2bf(acc[mt][nt][r] + bv);
        }
      }
  } else {
    int kvid = id - 512;
    int zi = kvid & 3, nb = (kvid >> 2) & 1, mi = kvid >> 3;
    const u16* Am = nb ? vb  : kb;
    const u16* Bm = nb ? WvT : WkT;
    gemm_core_db(Am, Bm, 2048, 2048, mi*128, 0, zi*512, zi*512+512, As, Bs, acc);
    float* dst = part + (size_t)(zi*2 + nb)*524288;   // [z][nb][4096][128]
    #pragma unroll
    for (int mt=0;mt<4;mt++)
      #pragma unroll
      for (int nt=0;nt<4;nt++){
        int col = wc*64 + nt*16 + c16;
        #pragma unroll
        for (int r=0;r<4;r++){
          int row = mi*128 + wr*64 + mt*16 + q*4 + r;
          dst[(size_t)row*128 + col] = acc[mt][nt][r];
        }
      }
  }
}

// ---------------- O-projection GEMM + bias, fp32 out ----------------
__global__ __launch_bounds__(256) void oproj_kernel(
    const u16* __restrict__ A, const u16* __restrict__ BT, const float* __restrict__ bias,
    float* __restrict__ C)
{
  __shared__ u16 As[2*4096], Bs[2*4096];
  f32x4 acc[4][4];
  f32x4 z = {0.f,0.f,0.f,0.f};
  #pragma unroll
  for (int i=0;i<4;i++) for (int j=0;j<4;j++) acc[i][j] = z;
  int m0 = blockIdx.x*128, n0 = blockIdx.y*128;
  gemm_core_db(A, BT, 2048, 2048, m0, n0, 0, 2048, As, Bs, acc);
  const int t = threadIdx.x, w = t>>6, l = t&63, wr = w>>1, wc = w&1, c16 = l&15, q = l>>4;
  #pragma unroll
  for (int mt=0;mt<4;mt++)
    #pragma unroll
    for (int nt=0;nt<4;nt++){
      int col = n0 + wc*64 + nt*16 + c16;
      float bv = bias[col];
      #pragma unroll
      for (int r=0;r<4;r++){
        int row = m0 + wr*64 + mt*16 + q*4 + r;
        C[(size_t)row*D_MODEL + col] = acc[mt][nt][r] + bv;
      }
    }
}

// ---------------- reduce split-K partials; Kp bf16 [4096][128], VpT bf16 [B][128][S] ----------------
__global__ __launch_bounds__(256) void kv_reduce_kernel(
    const float* __restrict__ part, const float* __restrict__ bk, const float* __restrict__ bv,
    u16* __restrict__ Kp, u16* __restrict__ VpT){
  int idx = blockIdx.x*256 + threadIdx.x;
  int d = idx & 127, sg = idx >> 7;
  float ka = 0.f, va = 0.f;
  #pragma unroll
  for (int zi=0; zi<4; zi++){
    ka += part[(size_t)(zi*2+0)*524288 + idx];
    va += part[(size_t)(zi*2+1)*524288 + idx];
  }
  Kp[idx] = f2bf(ka + bk[d]);
  int b = sg >> 11, sl = sg & 2047;
  VpT[(size_t)b*262144 + (size_t)d*2048 + sl] = f2bf(va + bv[d]);
}

// ---------------- flash attention v7 ----------------
// 8 waves x 32 q-rows (2 q-sets); block covers 256 q-rows; grid (8,32)=256
// blocks = 1/CU. Each K/V LDS fragment read feeds BOTH q-sets (2 MFMAs).
// Q frags loaded global->reg directly (wave collectively covers whole rows,
// L1/L2 absorb the per-lane scatter). V_kt gll at iter top (drained by
// mid-barrier); K_{kt+1} gll after mid-barrier (drained by end-barrier).
// PV uses merged K=32 MFMA via lane-held k-permutation (exact; see v6).
// LDS 64 KB: Ks[128key][128d] | Vs[128d][128k], chunk8-XOR swizzled.
__global__ __launch_bounds__(512, 2) void attn_kernel(
    const u16* __restrict__ Qp, const u16* __restrict__ Kp,
    const u16* __restrict__ VpT, u16* __restrict__ attnb){
  __shared__ u16 lds[32768];
  u16* Ks = lds;            // 128 x 128
  u16* Vs = lds + 16384;    // 128 x 128 (V^T)
  const int t = threadIdx.x;
  const int w = t >> 6, l = t & 63;
  const int c16 = l & 15, q = l >> 4;

  const int qt = blockIdx.x;           // 0..7
  const int bh = blockIdx.y;           // 0..31
  const int b = bh >> 4, h = bh & 15;

  const u16* Qbase = Qp  + ((size_t)(b*SEQ + qt*256 + w*32))*D_MODEL + h*HD;
  const u16* Kbase = Kp  + (size_t)(b*SEQ)*HD;
  const u16* Vbase = VpT + (size_t)b*HD*SEQ;

  // ---- prologue: issue K tile 0 gll; Q frags global->reg ----
  #pragma unroll
  for (int j=0;j<4;j++){
    int r = j*32 + w*4 + (l >> 4);
    int g = (l & 15) ^ (r & 15);
    gll16(Kbase + (size_t)r*HD + g*8, Ks + j*4096 + w*512);
  }
  bf16x8 qf[2][4];
  #pragma unroll
  for (int qs=0;qs<2;qs++)
    #pragma unroll
    for (int kk=0;kk<4;kk++)
      qf[qs][kk] = *(const bf16x8*)(Qbase + (size_t)(qs*16 + c16)*D_MODEL + (kk*4 + q)*8);
  __syncthreads();   // K0 arrived

  f32x4 o[2][8];
  f32x4 z4 = {0.f,0.f,0.f,0.f};
  #pragma unroll
  for (int qs=0;qs<2;qs++) for (int dt=0;dt<8;dt++) o[qs][dt] = z4;
  float mrow[2] = {-1e30f, -1e30f};
  float lrow[2] = {0.f, 0.f};
  const float cs = 0.08838834764831845f * 1.4426950408889634f;  // (1/sqrt(128))*log2(e)

  for (int kt = 0; kt < 16; kt++){
    // issue V_kt gll now — overlaps QK + softmax; drained by mid-barrier
    #pragma unroll
    for (int j=0;j<4;j++){
      int d = j*32 + w*4 + (l >> 4);
      int g = (l & 15) ^ (d & 15);
      gll16(Vbase + (size_t)d*SEQ + kt*128 + g*8, Vs + j*4096 + w*512);
    }

    // S^T = K Q^T : each kf LDS read feeds both q-sets
    f32x4 s[2][8];
    #pragma unroll
    for (int qs=0;qs<2;qs++) for (int kt8=0;kt8<8;kt8++) s[qs][kt8] = z4;
    __builtin_amdgcn_s_setprio(1);
    #pragma unroll
    for (int kt8=0; kt8<8; kt8++){
      #pragma unroll
      for (int kk=0;kk<4;kk++){
        int ch = kk*4 + q;
        bf16x8 kf = *(const bf16x8*)(Ks + (kt8*16 + c16)*128 + ((ch ^ c16) & 15)*8);
        s[0][kt8] = __builtin_amdgcn_mfma_f32_16x16x32_bf16(kf, qf[0][kk], s[0][kt8], 0,0,0);
        s[1][kt8] = __builtin_amdgcn_mfma_f32_16x16x32_bf16(kf, qf[1][kk], s[1][kt8], 0,0,0);
      }
    }
    __builtin_amdgcn_s_setprio(0);

    // online softmax per q-set (tree-form reductions)
    float alpha[2];
    #pragma unroll
    for (int qs=0; qs<2; qs++){
      float x[8];
      #pragma unroll
      for (int kt8=0;kt8<8;kt8++)
        x[kt8] = fmaxf(fmaxf(s[qs][kt8][0],s[qs][kt8][1]), fmaxf(s[qs][kt8][2],s[qs][kt8][3]));
      float vmax = fmaxf(fmaxf(fmaxf(x[0],x[1]),fmaxf(x[2],x[3])),
                         fmaxf(fmaxf(x[4],x[5]),fmaxf(x[6],x[7])));
      vmax = fmaxf(vmax, __shfl_xor(vmax, 16));
      vmax = fmaxf(vmax, __shfl_xor(vmax, 32));
      float mnew = fmaxf(mrow[qs], vmax);
      alpha[qs] = exp2f((mrow[qs] - mnew)*cs);
      float mc = mnew*cs;
      float rs[8];
      #pragma unroll
      for (int kt8=0;kt8<8;kt8++){
        float p0 = exp2f(__builtin_fmaf(s[qs][kt8][0], cs, -mc));
        float p1 = exp2f(__builtin_fmaf(s[qs][kt8][1], cs, -mc));
        float p2 = exp2f(__builtin_fmaf(s[qs][kt8][2], cs, -mc));
        float p3 = exp2f(__builtin_fmaf(s[qs][kt8][3], cs, -mc));
        s[qs][kt8][0]=p0; s[qs][kt8][1]=p1; s[qs][kt8][2]=p2; s[qs][kt8][3]=p3;
        rs[kt8] = (p0+p1)+(p2+p3);
      }
      float rsum = ((rs[0]+rs[1])+(rs[2]+rs[3])) + ((rs[4]+rs[5])+(rs[6]+rs[7]));
      rsum += __shfl_xor(rsum, 16);
      rsum += __shfl_xor(rsum, 32);
      lrow[qs] = lrow[qs]*alpha[qs] + rsum;
      mrow[qs] = mnew;
    }

    // rescale O (skip when no lane's max moved — exact)
    unsigned long long allone = __ballot(alpha[0] == 1.f && alpha[1] == 1.f);
    if (allone != ~0ull){
      #pragma unroll
      for (int qs=0;qs<2;qs++)
        #pragma unroll
        for (int dt=0;dt<8;dt++)
          #pragma unroll
          for (int r=0;r<4;r++) o[qs][dt][r] *= alpha[qs];
    }

    // pack P to bf16: P32[qs][kb] = B-operand for the kb-th 32-k block
    // (slots 0..3 = k 32kb+4q+r, slots 4..7 = k 32kb+16+4q+r)
    union PU { unsigned u[4]; bf16x8 v; } P32[2][4];
    #pragma unroll
    for (int qs=0;qs<2;qs++)
      #pragma unroll
      for (int kb=0;kb<4;kb++){
        P32[qs][kb].u[0] = pack2bf(s[qs][2*kb][0],   s[qs][2*kb][1]);
        P32[qs][kb].u[1] = pack2bf(s[qs][2*kb][2],   s[qs][2*kb][3]);
        P32[qs][kb].u[2] = pack2bf(s[qs][2*kb+1][0], s[qs][2*kb+1][1]);
        P32[qs][kb].u[3] = pack2bf(s[qs][2*kb+1][2], s[qs][2*kb+1][3]);
      }

    __syncthreads();   // mid: V_kt arrived; all QK reads of Ks done

    // issue K_{kt+1} gll now — overlaps PV; drained by end-barrier
    if (kt < 15){
      #pragma unroll
      for (int j=0;j<4;j++){
        int r = j*32 + w*4 + (l >> 4);
        int g = (l & 15) ^ (r & 15);
        gll16(Kbase + (size_t)((kt+1)*128 + r)*HD + g*8, Ks + j*4096 + w*512);
      }
    }

    // O^T += V^T P^T : each vf LDS read feeds both q-sets
    __builtin_amdgcn_s_setprio(1);
    #pragma unroll
    for (int kb=0; kb<4; kb++){
      int ca = 4*kb + (q>>1);       // chunk for k=32kb+4q (half q&1)
      int cb = ca + 2;              // chunk for k=32kb+16+4q
      #pragma unroll
      for (int dt=0; dt<8; dt++){
        int d = dt*16 + c16;
        union VU { bf16x4 h[2]; bf16x8 v; } vf;
        vf.h[0] = *(const bf16x4*)(Vs + d*128 + ((ca ^ c16) & 15)*8 + (q&1)*4);
        vf.h[1] = *(const bf16x4*)(Vs + d*128 + ((cb ^ c16) & 15)*8 + (q&1)*4);
        o[0][dt] = __builtin_amdgcn_mfma_f32_16x16x32_bf16(vf.v, P32[0][kb].v, o[0][dt], 0,0,0);
        o[1][dt] = __builtin_amdgcn_mfma_f32_16x16x32_bf16(vf.v, P32[1][kb].v, o[1][dt], 0,0,0);
      }
    }
    __builtin_amdgcn_s_setprio(0);
    __syncthreads();   // end: K_{kt+1} arrived; all PV reads of Vs done
  }

  // normalize + write: lane holds O[q=c16+16qs][d=dt*16+quad*4+r] -> ushort4 along d
  #pragma unroll
  for (int qs=0;qs<2;qs++){
    float inv = 1.f / lrow[qs];
    int qrow = qt*256 + w*32 + qs*16 + c16;
    u16* dst = attnb + ((size_t)(b*SEQ) + qrow)*D_MODEL + h*HD + q*4;
    #pragma unroll
    for (int dt=0;dt<8;dt++){
      ushort4 pk;
      pk.x = f2bf(o[qs][dt][0]*inv);
      pk.y = f2bf(o[qs][dt][1]*inv);
      pk.z = f2bf(o[qs][dt][2]*inv);
      pk.w = f2bf(o[qs][dt][3]*inv);
      *(ushort4*)(dst + dt*16) = pk;
    }
  }
}

extern "C" void kernel_launch(void* const* d_in, const int* in_sizes, int n_in,
                              void* d_out, int out_size, void* d_ws, size_t ws_size,
                              hipStream_t stream) {
  (void)in_sizes; (void)n_in; (void)out_size; (void)ws_size;
  const float* query = (const float*)d_in[0];
  const float* key   = (const float*)d_in[1];
  const float* value = (const float*)d_in[2];
  const float* Wq    = (const float*)d_in[3];
  const float* bq    = (const float*)d_in[4];
  const float* Wk    = (const float*)d_in[5];
  const float* bk    = (const float*)d_in[6];
  const float* Wv    = (const float*)d_in[7];
  const float* bv    = (const float*)d_in[8];
  const float* Wo    = (const float*)d_in[9];
  const float* bo    = (const float*)d_in[10];
  float* out = (float*)d_out;

  char* W = (char*)d_ws;
  u16*  qb     = (u16*) (W + 0);          // 16 MB  bf16 query [4096][2048]
  u16*  kb     = (u16*) (W + 16777216);   // 16 MB  bf16 key
  u16*  vb     = (u16*) (W + 33554432);   // 16 MB  bf16 value
  u16*  WqT    = (u16*) (W + 50331648);   //  8 MB  Wq^T  [2048][2048]
  u16*  WoT    = (u16*) (W + 58720256);   //  8 MB  Wo^T
  u16*  WkT    = (u16*) (W + 67108864);   // .5 MB  Wk^T  [128][2048]
  u16*  WvT    = (u16*) (W + 67633152);   // .5 MB  Wv^T
  u16*  Qp     = (u16*) (W + 68157440);   // 16 MB  Q proj bf16 [4096][2048]
  u16*  Kp     = (u16*) (W + 84934656);   //  1 MB  K proj bf16 [4096][128]
  u16*  VpT    = (u16*) (W + 85983232);   //  1 MB  V proj^T bf16 [B][128][2048]
  u16*  attnb  = (u16*) (W + 87031808);   // 16 MB  attention out bf16 [4096][2048]
  float* kvpart= (float*)(W + 103809024); // 16 MB  split-K partials [4][2][4096][128]

  convert3_kernel<<<8192, 256, 0, stream>>>(
      (const float4*)query, (const float4*)key, (const float4*)value,
      (ushort4*)qb, (ushort4*)kb, (ushort4*)vb);
  transpose_all<<<8704, 256, 0, stream>>>(Wq, Wo, Wk, Wv, WqT, WoT, WkT, WvT);
  proj_kernel<<<768, 256, 0, stream>>>(qb, kb, vb, WqT, WkT, WvT, bq, Qp, kvpart);
  kv_reduce_kernel<<<2048, 256, 0, stream>>>(kvpart, bk, bv, Kp, VpT);
  attn_kernel<<<dim3(8,32), 512, 0, stream>>>(Qp, Kp, VpT, attnb);
  oproj_kernel<<<dim3(32,16), 256, 0, stream>>>(attnb, WoT, bo, out);
}